// Round 3
// baseline (375.605 us; speedup 1.0000x reference)
//
#include <hip/hip_runtime.h>

// Correlation layer (FlowNet-style), MAX_DISP=4 -> 81 displacements.
// out[b, d, y, x] = sum_c f1[b,c,y,x] * f2[b,c, y+dy-4, x+dx-4], d = dy*9+dx
//
// R3 design: NO LDS, NO barriers (R2 was latency-bound: VALUBusy 22%,
// 64 vmcnt(0)-draining barriers per block, 9 waves/CU).
//  - one block per (ytile, dy, b): grid 16 x 9 x 8, 128 threads.
//  - thread owns 4 consecutive x of 4 y-rows tile; per channel it loads
//    f1 (1 float4) + the 12-float f2 window (3 aligned float4) directly from
//    global (L1/L2-served; neighboring lanes overlap), does 36 FMAs.
//  - dy-OOB rows: whole output row is zero -> skip loop.
//  - x-halo: clamped load addresses + multiply-mask w0/w2 by {0,1}.
//  - 32-bit offsets off uniform per-batch bases -> saddr+voffset addressing.

namespace {
constexpr int B_ = 8, C_ = 256, H_ = 64, W_ = 128;
constexpr int SIDE = 9, ND = 81, PAD = 4;
constexpr int HW = H_ * W_;
}

__global__ __launch_bounds__(128, 4)
void corr_kernel(const float* __restrict__ f1, const float* __restrict__ f2,
                 float* __restrict__ out) {
  const int t = threadIdx.x;
  const int txg = t & 31;   // x-group: covers x = txg*4 .. txg*4+3
  const int ty = t >> 5;    // 0..3
  const int ytile = blockIdx.x;
  const int dy = blockIdx.y;
  const int b = blockIdx.z;

  const int y = ytile * 4 + ty;
  const int yg = y + dy - PAD;   // f2 row for this thread (fixed per thread)
  const int x0 = txg * 4;

  float acc[SIDE][4];
#pragma unroll
  for (int dx = 0; dx < SIDE; ++dx)
#pragma unroll
    for (int p = 0; p < 4; ++p) acc[dx][p] = 0.f;

  if (yg >= 0 && yg < H_) {
    const float* __restrict__ f1b = f1 + (size_t)b * C_ * HW;
    const float* __restrict__ f2b = f2 + (size_t)b * C_ * HW;
    const float mlo = (txg > 0) ? 1.f : 0.f;   // w0 valid?
    const float mhi = (txg < 31) ? 1.f : 0.f;  // w2 valid?

    unsigned o1 = (unsigned)(y * W_ + x0);          // f1 offset
    unsigned o2 = (unsigned)(yg * W_ + x0);         // f2 center
    unsigned o2m = o2 - (txg > 0 ? 4u : 0u);        // clamped left window
    unsigned o2p = o2 + (txg < 31 ? 4u : 0u);       // clamped right window

#pragma unroll 4
    for (int c = 0; c < C_; ++c) {
      const float4 a = *(const float4*)(f1b + o1);
      float4 w0 = *(const float4*)(f2b + o2m);
      const float4 w1 = *(const float4*)(f2b + o2);
      float4 w2 = *(const float4*)(f2b + o2p);
      o1 += HW; o2 += HW; o2m += HW; o2p += HW;

      // mask halo windows (boundary lanes loaded clamped/duplicate data)
      w0.x *= mlo; w0.y *= mlo; w0.z *= mlo; w0.w *= mlo;
      w2.x *= mhi; w2.y *= mhi; w2.z *= mhi; w2.w *= mhi;

      const float av[4] = {a.x, a.y, a.z, a.w};
      const float wv[12] = {w0.x, w0.y, w0.z, w0.w, w1.x, w1.y, w1.z, w1.w,
                            w2.x, w2.y, w2.z, w2.w};
#pragma unroll
      for (int dx = 0; dx < SIDE; ++dx)
#pragma unroll
        for (int p = 0; p < 4; ++p)
          acc[dx][p] += av[p] * wv[dx + p];
    }
  }

  // ---- epilogue: each output element written exactly once, float4 stores ----
#pragma unroll
  for (int dx = 0; dx < SIDE; ++dx) {
    const int d = dy * SIDE + dx;
    float* po = out + ((size_t)(b * ND + d) * H_ + y) * W_ + x0;
    *(float4*)po = make_float4(acc[dx][0], acc[dx][1], acc[dx][2], acc[dx][3]);
  }
}

extern "C" void kernel_launch(void* const* d_in, const int* in_sizes, int n_in,
                              void* d_out, int out_size, void* d_ws, size_t ws_size,
                              hipStream_t stream) {
  const float* f1 = (const float*)d_in[0];
  const float* f2 = (const float*)d_in[1];
  float* out = (float*)d_out;

  dim3 grid(H_ / 4, SIDE, B_);  // 16 x 9 x 8 = 1152 blocks
  corr_kernel<<<grid, 128, 0, stream>>>(f1, f2, out);
}

// Round 4
// 264.964 us; speedup vs baseline: 1.4176x; 1.4176x over previous
//
#include <hip/hip_runtime.h>

// Correlation layer (FlowNet-style), MAX_DISP=4 -> 81 displacements.
// out[b, d, y, x] = sum_c f1[b,c,y,x] * f2[b,c, y+dy-4, x+dx-4], d = dy*9+dx
//
// R4 design: fix grid-starved occupancy (R1-R3 all ~2.25 waves/SIMD, VALU 13-22%).
//  - 512-thread blocks = 4 channel-groups x 128 threads; grid 16 x 9 x 8 stays
//    1152 blocks -> 9216 waves = 9 waves/SIMD.
//  - each group accumulates 64 channels into acc[9][4] (global->reg loads,
//    no in-loop masks); 3-barrier LDS tree combines groups; group 0 stores.
//  - halo handled at epilogue: acc[dx][p] uses window elem j=dx+p exactly once,
//    so boundary lanes just zero the invalid j entries after reduction.
//  - LDS reduce layout transposed [i][tl]: stride-1 -> conflict-free.

namespace {
constexpr int B_ = 8, C_ = 256, H_ = 64, W_ = 128;
constexpr int SIDE = 9, ND = 81, PAD = 4;
constexpr int HW = H_ * W_;
constexpr int CPG = C_ / 4;   // 64 channels per group
}

__global__ __launch_bounds__(512, 6)
void corr_kernel(const float* __restrict__ f1, const float* __restrict__ f2,
                 float* __restrict__ out) {
  __shared__ float red[2][36 * 128];   // 36.9 KB

  const int t = threadIdx.x;
  const int g = t >> 7;     // channel group 0..3
  const int tl = t & 127;   // lane within group
  const int txg = tl & 31;  // x-group: covers x = txg*4 .. txg*4+3
  const int ty = tl >> 5;   // 0..3
  const int ytile = blockIdx.x;
  const int dy = blockIdx.y;
  const int b = blockIdx.z;

  const int y = ytile * 4 + ty;
  const int yg = y + dy - PAD;   // f2 row for this thread
  const int x0 = txg * 4;

  float acc[SIDE][4];
#pragma unroll
  for (int dx = 0; dx < SIDE; ++dx)
#pragma unroll
    for (int p = 0; p < 4; ++p) acc[dx][p] = 0.f;

  if (yg >= 0 && yg < H_) {
    const float* __restrict__ f1b = f1 + ((size_t)b * C_ + g * CPG) * HW;
    const float* __restrict__ f2b = f2 + ((size_t)b * C_ + g * CPG) * HW;

    unsigned o1 = (unsigned)(y * W_ + x0);          // f1 offset
    unsigned o2 = (unsigned)(yg * W_ + x0);         // f2 center window
    unsigned o2m = o2 - (txg > 0 ? 4u : 0u);        // clamped left window
    unsigned o2p = o2 + (txg < 31 ? 4u : 0u);       // clamped right window

#pragma unroll 2
    for (int c = 0; c < CPG; ++c) {
      const float4 a = *(const float4*)(f1b + o1);
      const float4 w0 = *(const float4*)(f2b + o2m);
      const float4 w1 = *(const float4*)(f2b + o2);
      const float4 w2 = *(const float4*)(f2b + o2p);
      o1 += HW; o2 += HW; o2m += HW; o2p += HW;

      const float av[4] = {a.x, a.y, a.z, a.w};
      const float wv[12] = {w0.x, w0.y, w0.z, w0.w, w1.x, w1.y, w1.z, w1.w,
                            w2.x, w2.y, w2.z, w2.w};
#pragma unroll
      for (int dx = 0; dx < SIDE; ++dx)
#pragma unroll
        for (int p = 0; p < 4; ++p)
          acc[dx][p] += av[p] * wv[dx + p];
    }
  }

  // ---- cross-group reduction: 4 partials -> group 0, 3 barriers ----
  if (g >= 2) {
    float* d = red[g - 2];
#pragma unroll
    for (int i = 0; i < 36; ++i) d[i * 128 + tl] = acc[i >> 2][i & 3];
  }
  __syncthreads();
  if (g < 2) {
    const float* s = red[g];
#pragma unroll
    for (int i = 0; i < 36; ++i) acc[i >> 2][i & 3] += s[i * 128 + tl];
  }
  __syncthreads();
  if (g == 1) {
    float* d = red[0];
#pragma unroll
    for (int i = 0; i < 36; ++i) d[i * 128 + tl] = acc[i >> 2][i & 3];
  }
  __syncthreads();
  if (g == 0) {
    const float* s = red[0];
#pragma unroll
    for (int i = 0; i < 36; ++i) acc[i >> 2][i & 3] += s[i * 128 + tl];

    // halo fix-up: window elem j = dx+p -> f2 x = x0 + j - 4
    if (txg == 0) {
#pragma unroll
      for (int dx = 0; dx < SIDE; ++dx)
#pragma unroll
        for (int p = 0; p < 4; ++p)
          if (dx + p < 4) acc[dx][p] = 0.f;
    }
    if (txg == 31) {
#pragma unroll
      for (int dx = 0; dx < SIDE; ++dx)
#pragma unroll
        for (int p = 0; p < 4; ++p)
          if (dx + p >= 8) acc[dx][p] = 0.f;
    }

    // each output element written exactly once, float4 stores
#pragma unroll
    for (int dx = 0; dx < SIDE; ++dx) {
      const int d = dy * SIDE + dx;
      float* po = out + ((size_t)(b * ND + d) * H_ + y) * W_ + x0;
      *(float4*)po = make_float4(acc[dx][0], acc[dx][1], acc[dx][2], acc[dx][3]);
    }
  }
}

extern "C" void kernel_launch(void* const* d_in, const int* in_sizes, int n_in,
                              void* d_out, int out_size, void* d_ws, size_t ws_size,
                              hipStream_t stream) {
  const float* f1 = (const float*)d_in[0];
  const float* f2 = (const float*)d_in[1];
  float* out = (float*)d_out;

  dim3 grid(H_ / 4, SIDE, B_);  // 16 x 9 x 8 = 1152 blocks of 512
  corr_kernel<<<grid, 512, 0, stream>>>(f1, f2, out);
}

// Round 5
// 229.739 us; speedup vs baseline: 1.6349x; 1.1533x over previous
//
#include <hip/hip_runtime.h>

// Correlation layer via banded bf16 MFMA (gfx950).
// out[b, dy*9+dx, y, x] = sum_c f1[b,c,y,x] * f2[b,c,y+dy-4,x+dx-4]
//
// corr(m-px, n-px) = sum_c F1[m][c]*F2[n][c] == mfma_f32_16x16x32_bf16 with
// A = F1 tile [16 px][K], B = F2 tile [16 px][K] (B^T-style contraction).
// Per M-tile (16 px of one row) and dy: two B-tiles at x-offsets -4 and +12
// cover all 9 diagonals: dx = n-m (tile0, 0<=dx<=8), dx = n-m+16 (tile1).
//
// Block: (x-half, y, b) = 64 px of one row; 512 thr = 8 waves =
//        4 M-tiles x 2 dy-halves (dy 0-4 / 5-8).
// K-loop: 8 chunks of 32 ch; fp32->bf16 packed into LDS each chunk.
// LDS px-stride = 80 B (5x16B blocks, 16B frag at q*16): stride 20 banks ->
// uniform 2-way on both ds_read_b128 and staging ds_write_b32 (free, m136).
// Halos (dy-row OOB, x OOB) zero-filled -> no epilogue masking needed.

namespace {
constexpr int B_ = 8, C_ = 256, H_ = 64, W_ = 128;
constexpr int SIDE = 9, ND = 81, PAD = 4;
constexpr int HW = H_ * W_;
constexpr int PXS = 20;            // uints per px row (16 used + 4 pad) = 80 B
constexpr int F2PX = 80;           // f2 staged px: x in [x0B-4, x0B+76)
constexpr int F1PX = 64;
constexpr int KC = 32;             // channels per chunk (one MFMA K)
constexpr int NCH = C_ / KC;       // 8 chunks
// staging unit = ch-pair x px-quad: 2 global float4 -> 4 packed b32 LDS writes
constexpr int F2U = SIDE * (F2PX / 4) * (KC / 2);  // 9*20*16 = 2880
constexpr int F1U = (F1PX / 4) * (KC / 2);         // 16*16   = 256
constexpr int NU = F2U + F1U;                      // 3136
}

typedef __attribute__((ext_vector_type(8))) short short8;
typedef __attribute__((ext_vector_type(4))) float float4v;

__device__ __forceinline__ unsigned bf16rne(float f) {
  unsigned u = __float_as_uint(f);
  return (u + 0x7fffu + ((u >> 16) & 1u)) >> 16;
}
__device__ __forceinline__ unsigned packbf2(float lo, float hi) {
  return bf16rne(lo) | (bf16rne(hi) << 16);
}

__global__ __launch_bounds__(512, 4)
void corr_kernel(const float* __restrict__ f1, const float* __restrict__ f2,
                 float* __restrict__ out) {
  __shared__ __align__(16) unsigned f2s[SIDE * F2PX * PXS];  // 57600 B
  __shared__ __align__(16) unsigned f1s[F1PX * PXS];         //  5120 B

  const int t = threadIdx.x;
  const int bx = blockIdx.x;   // x half: 0 or 1
  const int by = blockIdx.y;   // y row
  const int b = blockIdx.z;
  const int x0B = bx * 64;

  const int lane = t & 63;
  const int wv = t >> 6;       // wave 0..7
  const int wt = wv >> 1;      // M-tile 0..3 (x = x0B + 16*wt ..)
  const int half = wv & 1;     // dy half
  const int dyb = half * 5;
  const int ndy = 5 - half;    // 5 or 4 dy rows

  const int v = lane & 15;     // frag pixel index (m for A, n for B/C-col)
  const int q = lane >> 4;     // k-quad / C-row-group

  float4v acc0[5], acc1[5];
#pragma unroll
  for (int i = 0; i < 5; ++i) {
    acc0[i] = (float4v){0.f, 0.f, 0.f, 0.f};
    acc1[i] = (float4v){0.f, 0.f, 0.f, 0.f};
  }

  const float* __restrict__ f1b = f1 + (size_t)b * C_ * HW;
  const float* __restrict__ f2b = f2 + (size_t)b * C_ * HW;

  for (int ch = 0; ch < NCH; ++ch) {
    const int c0 = ch * KC;
    if (ch) __syncthreads();  // compute on previous chunk must finish

    // ---- stage chunk: fp32 -> packed bf16 pairs in LDS ----
    for (int u = t; u < NU; u += 512) {
      if (u < F2U) {
        const int cp = u & 15;          // ch pair (k = 2cp, 2cp+1)
        const int rp = u >> 4;
        const int pxq = rp % 20;        // px quad
        const int r = rp / 20;          // f2 row = dy index
        const int yg = by + r - PAD;
        const int xb = x0B - PAD + pxq * 4;
        float4 va = make_float4(0.f, 0.f, 0.f, 0.f);
        float4 vb = va;
        if (yg >= 0 && yg < H_ && xb >= 0 && xb <= W_ - 4) {
          const float* p = f2b + ((size_t)(c0 + 2 * cp) * H_ + yg) * W_ + xb;
          va = *(const float4*)p;
          vb = *(const float4*)(p + HW);
        }
        unsigned* d = &f2s[(r * F2PX + pxq * 4) * PXS + cp];
        d[0 * PXS] = packbf2(va.x, vb.x);
        d[1 * PXS] = packbf2(va.y, vb.y);
        d[2 * PXS] = packbf2(va.z, vb.z);
        d[3 * PXS] = packbf2(va.w, vb.w);
      } else {
        const int u2 = u - F2U;
        const int cp = u2 & 15;
        const int pxq = u2 >> 4;        // 0..15, x = x0B + 4*pxq (always valid)
        const float* p =
            f1b + ((size_t)(c0 + 2 * cp) * H_ + by) * W_ + x0B + pxq * 4;
        const float4 va = *(const float4*)p;
        const float4 vb = *(const float4*)(p + HW);
        unsigned* d = &f1s[(pxq * 4) * PXS + cp];
        d[0 * PXS] = packbf2(va.x, vb.x);
        d[1 * PXS] = packbf2(va.y, vb.y);
        d[2 * PXS] = packbf2(va.z, vb.z);
        d[3 * PXS] = packbf2(va.w, vb.w);
      }
    }
    __syncthreads();

    // ---- compute: A frag once, per dy two B frags + two MFMAs ----
    const short8 af =
        __builtin_bit_cast(short8, *(const uint4*)&f1s[(16 * wt + v) * PXS + 4 * q]);
#pragma unroll
    for (int i = 0; i < 5; ++i) {
      if (i < ndy) {
        const int dy = dyb + i;
        const unsigned* fb = &f2s[(dy * F2PX + 16 * wt + v) * PXS + 4 * q];
        const short8 b0 = __builtin_bit_cast(short8, *(const uint4*)fb);
        const short8 b1 = __builtin_bit_cast(short8, *(const uint4*)(fb + 16 * PXS));
        acc0[i] = __builtin_amdgcn_mfma_f32_16x16x32_bf16(af, b0, acc0[i], 0, 0, 0);
        acc1[i] = __builtin_amdgcn_mfma_f32_16x16x32_bf16(af, b1, acc1[i], 0, 0, 0);
      }
    }
  }

  // ---- epilogue: band extraction, each output written exactly once ----
  // C/D layout: col n = lane&15, row m = q*4 + reg.
#pragma unroll
  for (int i = 0; i < 5; ++i) {
    if (i < ndy) {
      const int dy = dyb + i;
#pragma unroll
      for (int r = 0; r < 4; ++r) {
        const int m = q * 4 + r;
        const int x = x0B + 16 * wt + m;
        const int dx0 = v - m;           // tile0: dx in [0,8] when 0<=n-m<=8
        if (dx0 >= 0 && dx0 <= 8)
          out[(((size_t)b * ND + dy * SIDE + dx0) * H_ + by) * W_ + x] = acc0[i][r];
        const int dx1 = v - m + 16;      // tile1: dx in [1,8] when n-m<=-8
        if (dx1 <= 8)
          out[(((size_t)b * ND + dy * SIDE + dx1) * H_ + by) * W_ + x] = acc1[i][r];
      }
    }
  }
}

extern "C" void kernel_launch(void* const* d_in, const int* in_sizes, int n_in,
                              void* d_out, int out_size, void* d_ws, size_t ws_size,
                              hipStream_t stream) {
  const float* f1 = (const float*)d_in[0];
  const float* f2 = (const float*)d_in[1];
  float* out = (float*)d_out;

  dim3 grid(2, H_, B_);  // 2 x 64 x 8 = 1024 blocks of 512
  corr_kernel<<<grid, 512, 0, stream>>>(f1, f2, out);
}

// Round 6
// 216.453 us; speedup vs baseline: 1.7353x; 1.0614x over previous
//
#include <hip/hip_runtime.h>

// Correlation layer via banded bf16 MFMA, two-pass (gfx950).
// out[b, dy*9+dx, y, x] = sum_c f1[b,c,y,x] * f2[b,c,y+dy-4,x+dx-4]
//
// R6: R5 was bound by redundant fp32->bf16 staging (every y-block converted
// its 9 f2 rows: ~9x conversion + 248 MB refetch, VALU 29%, Mfma 2.6%).
// Fix: pass 1 converts f2 ONCE into a padded, fragment-ready bf16 layout in
// d_ws: [b][c/8][y'=72][x'=144][c%8] (zero halos baked in). All B-tiles sit
// at x' = 16j, j=0..8 (they tile exactly), so pass 2 loads each B-fragment
// as one aligned dwordx4 per lane straight from global -> no LDS, no barriers.
// A-fragments come from fp32 f1 directly (8 dword loads + 4 packs per chunk).
// Falls back to the R5 single-kernel path if ws_size is too small.

namespace {
constexpr int B_ = 8, C_ = 256, H_ = 64, W_ = 128;
constexpr int SIDE = 9, ND = 81, PAD = 4;
constexpr int HW = H_ * W_;
constexpr int CB = 32;              // channel-blocks of 8
constexpr int HP = 72, WP = 144;    // padded f2 dims (y' = y+dy, x' = x+4)
constexpr size_t BWS_U4 = (size_t)B_ * CB * HP * WP;  // one uint4 per px
constexpr size_t BWS_BYTES = BWS_U4 * 16;             // 42.5 MB
}

typedef __attribute__((ext_vector_type(8))) short short8;
typedef __attribute__((ext_vector_type(4))) float float4v;

__device__ __forceinline__ unsigned bf16rne(float f) {
  unsigned u = __float_as_uint(f);
  return (u + 0x7fffu + ((u >> 16) & 1u)) >> 16;
}
__device__ __forceinline__ unsigned packbf2(float lo, float hi) {
  return bf16rne(lo) | (bf16rne(hi) << 16);
}

// ---------------- pass 1: f2 fp32 -> padded fragment-ready bf16 ----------------
__global__ __launch_bounds__(256)
void cvt_f2(const float* __restrict__ f2, uint4* __restrict__ bws) {
  const int tid = blockIdx.x * 256 + threadIdx.x;
  const int xq = tid % (WP / 4);        // px-quad 0..35
  int r = tid / (WP / 4);
  const int yp = r % HP;
  r /= HP;
  const int cb = r % CB;
  const int b = r / CB;

  uint4 o[4] = {};
  const int yg = yp - PAD;
  const int x = xq * 4 - PAD;           // pad quads (xq==0, xq>=33) fully OOB
  if (yg >= 0 && yg < H_ && x >= 0 && x + 3 < W_) {
    const float* s = f2 + ((size_t)(b * C_ + cb * 8) * H_ + yg) * W_ + x;
    float vv[8][4];
#pragma unroll
    for (int e = 0; e < 8; ++e) {
      const float4 t = *(const float4*)(s + (size_t)e * HW);
      vv[e][0] = t.x; vv[e][1] = t.y; vv[e][2] = t.z; vv[e][3] = t.w;
    }
#pragma unroll
    for (int p = 0; p < 4; ++p) {
      o[p].x = packbf2(vv[0][p], vv[1][p]);
      o[p].y = packbf2(vv[2][p], vv[3][p]);
      o[p].z = packbf2(vv[4][p], vv[5][p]);
      o[p].w = packbf2(vv[6][p], vv[7][p]);
    }
  }
  uint4* d = bws + ((size_t)(b * CB + cb) * HP + yp) * WP + xq * 4;
#pragma unroll
  for (int p = 0; p < 4; ++p) d[p] = o[p];
}

// ---------------- pass 2: banded MFMA, fragments straight from global ----------
__global__ __launch_bounds__(256, 4)
void corr_mfma(const float* __restrict__ f1, const uint4* __restrict__ bws,
               float* __restrict__ out) {
  const int t = threadIdx.x;
  const int lane = t & 63;
  const int wv = t >> 6;                    // 0..3
  const int jm = blockIdx.x * 2 + (wv >> 1);  // M-tile 0..7 (x = 16*jm..)
  const int half = wv & 1;                  // dy half: 0 -> dy 0..4, 1 -> 5..8
  const int y = blockIdx.y;
  const int b = blockIdx.z;
  const int v = lane & 15;                  // fragment pixel index
  const int q = lane >> 4;                  // k-quad / C-row-group
  const int dyb = half * 5;
  const int ndy = 5 - half;

  float4v acc0[5], acc1[5];
#pragma unroll
  for (int i = 0; i < 5; ++i) {
    acc0[i] = (float4v){0.f, 0.f, 0.f, 0.f};
    acc1[i] = (float4v){0.f, 0.f, 0.f, 0.f};
  }

  // A: f1[b, q*8 + ch*32 + j, y, 16jm + v]  (8 scalar dwords per chunk)
  const float* a_base = f1 + ((size_t)(b * C_ + q * 8) * H_ + y) * W_ + 16 * jm + v;
  // B: bws[(b*CB + ch*4 + q), y + dy, 16*jm + v] (+16 px for tile1)
  const uint4* b_base = bws + ((size_t)(b * CB) + q) * (HP * WP) + 16 * jm + v;

  for (int ch = 0; ch < 8; ++ch) {
    float av[8];
#pragma unroll
    for (int j = 0; j < 8; ++j) av[j] = a_base[(size_t)(ch * 32 + j) * HW];
    uint4 afu;
    afu.x = packbf2(av[0], av[1]);
    afu.y = packbf2(av[2], av[3]);
    afu.z = packbf2(av[4], av[5]);
    afu.w = packbf2(av[6], av[7]);
    const short8 af = __builtin_bit_cast(short8, afu);

    const uint4* bc = b_base + (size_t)(ch * 4) * (HP * WP) + (size_t)(y + dyb) * WP;
#pragma unroll
    for (int i = 0; i < 5; ++i) {
      if (i < ndy) {
        const uint4* bp = bc + (size_t)i * WP;
        const short8 b0 = __builtin_bit_cast(short8, bp[0]);
        const short8 b1 = __builtin_bit_cast(short8, bp[16]);
        acc0[i] = __builtin_amdgcn_mfma_f32_16x16x32_bf16(af, b0, acc0[i], 0, 0, 0);
        acc1[i] = __builtin_amdgcn_mfma_f32_16x16x32_bf16(af, b1, acc1[i], 0, 0, 0);
      }
    }
  }

  // Epilogue: C/D col n = v, row m = q*4+reg. tile0: dx = n-m in [0,8];
  // tile1: dx = n-m+16 in [1,8]. Each output element written exactly once.
#pragma unroll
  for (int i = 0; i < 5; ++i) {
    if (i < ndy) {
      const int dy = dyb + i;
#pragma unroll
      for (int r = 0; r < 4; ++r) {
        const int m = q * 4 + r;
        const int x = 16 * jm + m;
        const int dx0 = v - m;
        if (dx0 >= 0 && dx0 <= 8)
          out[(((size_t)b * ND + dy * SIDE + dx0) * H_ + y) * W_ + x] = acc0[i][r];
        const int dx1 = v - m + 16;
        if (dx1 <= 8)
          out[(((size_t)b * ND + dy * SIDE + dx1) * H_ + y) * W_ + x] = acc1[i][r];
      }
    }
  }
}

// ---------------- fallback (R5 kernel) if ws_size is too small ----------------
namespace fb {
constexpr int PXS = 20, F2PX = 80, F1PX = 64, KC = 32, NCH = C_ / KC;
constexpr int F2U = SIDE * (F2PX / 4) * (KC / 2);
constexpr int F1U = (F1PX / 4) * (KC / 2);
constexpr int NU = F2U + F1U;
}

__global__ __launch_bounds__(512, 4)
void corr_fallback(const float* __restrict__ f1, const float* __restrict__ f2,
                   float* __restrict__ out) {
  using namespace fb;
  __shared__ __align__(16) unsigned f2s[SIDE * F2PX * PXS];
  __shared__ __align__(16) unsigned f1s[F1PX * PXS];

  const int t = threadIdx.x;
  const int bx = blockIdx.x, by = blockIdx.y, b = blockIdx.z;
  const int x0B = bx * 64;
  const int lane = t & 63, wv = t >> 6;
  const int wt = wv >> 1, half = wv & 1;
  const int dyb = half * 5, ndy = 5 - half;
  const int v = lane & 15, q = lane >> 4;

  float4v acc0[5], acc1[5];
#pragma unroll
  for (int i = 0; i < 5; ++i) {
    acc0[i] = (float4v){0.f, 0.f, 0.f, 0.f};
    acc1[i] = (float4v){0.f, 0.f, 0.f, 0.f};
  }
  const float* __restrict__ f1b = f1 + (size_t)b * C_ * HW;
  const float* __restrict__ f2b = f2 + (size_t)b * C_ * HW;

  for (int ch = 0; ch < NCH; ++ch) {
    const int c0 = ch * KC;
    if (ch) __syncthreads();
    for (int u = t; u < NU; u += 512) {
      if (u < F2U) {
        const int cp = u & 15;
        const int rp = u >> 4;
        const int pxq = rp % 20;
        const int r = rp / 20;
        const int yg = by + r - PAD;
        const int xb = x0B - PAD + pxq * 4;
        float4 va = make_float4(0.f, 0.f, 0.f, 0.f), vb = va;
        if (yg >= 0 && yg < H_ && xb >= 0 && xb <= W_ - 4) {
          const float* p = f2b + ((size_t)(c0 + 2 * cp) * H_ + yg) * W_ + xb;
          va = *(const float4*)p;
          vb = *(const float4*)(p + HW);
        }
        unsigned* d = &f2s[(r * F2PX + pxq * 4) * PXS + cp];
        d[0 * PXS] = packbf2(va.x, vb.x);
        d[1 * PXS] = packbf2(va.y, vb.y);
        d[2 * PXS] = packbf2(va.z, vb.z);
        d[3 * PXS] = packbf2(va.w, vb.w);
      } else {
        const int u2 = u - F2U;
        const int cp = u2 & 15;
        const int pxq = u2 >> 4;
        const float* p = f1b + ((size_t)(c0 + 2 * cp) * H_ + by) * W_ + x0B + pxq * 4;
        const float4 va = *(const float4*)p;
        const float4 vb = *(const float4*)(p + HW);
        unsigned* d = &f1s[(pxq * 4) * PXS + cp];
        d[0 * PXS] = packbf2(va.x, vb.x);
        d[1 * PXS] = packbf2(va.y, vb.y);
        d[2 * PXS] = packbf2(va.z, vb.z);
        d[3 * PXS] = packbf2(va.w, vb.w);
      }
    }
    __syncthreads();

    const short8 af =
        __builtin_bit_cast(short8, *(const uint4*)&f1s[(16 * wt + v) * PXS + 4 * q]);
#pragma unroll
    for (int i = 0; i < 5; ++i) {
      if (i < ndy) {
        const int dy = dyb + i;
        const unsigned* fbp = &f2s[(dy * F2PX + 16 * wt + v) * PXS + 4 * q];
        const short8 b0 = __builtin_bit_cast(short8, *(const uint4*)fbp);
        const short8 b1 = __builtin_bit_cast(short8, *(const uint4*)(fbp + 16 * PXS));
        acc0[i] = __builtin_amdgcn_mfma_f32_16x16x32_bf16(af, b0, acc0[i], 0, 0, 0);
        acc1[i] = __builtin_amdgcn_mfma_f32_16x16x32_bf16(af, b1, acc1[i], 0, 0, 0);
      }
    }
  }
#pragma unroll
  for (int i = 0; i < 5; ++i) {
    if (i < ndy) {
      const int dy = dyb + i;
#pragma unroll
      for (int r = 0; r < 4; ++r) {
        const int m = q * 4 + r;
        const int x = x0B + 16 * wt + m;
        const int dx0 = v - m;
        if (dx0 >= 0 && dx0 <= 8)
          out[(((size_t)b * ND + dy * SIDE + dx0) * H_ + by) * W_ + x] = acc0[i][r];
        const int dx1 = v - m + 16;
        if (dx1 <= 8)
          out[(((size_t)b * ND + dy * SIDE + dx1) * H_ + by) * W_ + x] = acc1[i][r];
      }
    }
  }
}

extern "C" void kernel_launch(void* const* d_in, const int* in_sizes, int n_in,
                              void* d_out, int out_size, void* d_ws, size_t ws_size,
                              hipStream_t stream) {
  const float* f1 = (const float*)d_in[0];
  const float* f2 = (const float*)d_in[1];
  float* out = (float*)d_out;

  if (ws_size >= BWS_BYTES) {
    uint4* bws = (uint4*)d_ws;
    const int n1 = (int)(BWS_U4 / 4);           // 663552 threads
    cvt_f2<<<dim3(n1 / 256), 256, 0, stream>>>(f2, bws);
    corr_mfma<<<dim3(4, H_, B_), 256, 0, stream>>>(f1, bws, out);
  } else {
    corr_fallback<<<dim3(2, H_, B_), 512, 0, stream>>>(f1, f2, out);
  }
}